// Round 1
// baseline (298.534 us; speedup 1.0000x reference)
//
#include <hip/hip_runtime.h>

// image2patch / im2col gather:
//   input  : (32, 8, 256, 256) fp32  -> viewed as 256 images of 256x256
//   output : (256, 3969, 64) fp32
//   patch p: row0 = 4*(p/63), col0 = 4*(p%63); 8x8 patch, row-major k.
//
// One thread per output float4 (16 chunks per patch):
//   k4 = chunk id in [0,16): di = k4>>1, dj4 = k4&1
//   read  in [n, 4*(p/63)+di, 4*(p%63)+4*dj4 .. +3]  (16B aligned: stride 4)
//   write out[gid]                                    (fully coalesced)

constexpr unsigned NPDIM   = 63;          // patch positions per dim
constexpr unsigned PATCHES = NPDIM * NPDIM; // 3969
constexpr unsigned CHUNKS  = 16;          // float4 chunks per 8x8 patch
constexpr unsigned NIMG    = 256;         // 32*8 images
// total float4s = 256 * 3969 * 16 = 16,257,024 = 63504 * 256

__global__ __launch_bounds__(256) void image2patch_kernel(
    const float4* __restrict__ in4, float4* __restrict__ out4) {
    unsigned gid = blockIdx.x * 256u + threadIdx.x;

    unsigned k4 = gid & 15u;       // chunk within patch
    unsigned pn = gid >> 4;        // n*3969 + p
    unsigned n  = pn / PATCHES;
    unsigned p  = pn - n * PATCHES;
    unsigned pr = p / NPDIM;
    unsigned pc = p - pr * NPDIM;

    unsigned row  = pr * 4u + (k4 >> 1);       // image row, 0..255
    unsigned col4 = pc + (k4 & 1u);            // image col / 4, 0..63

    // image is 256x256 floats = 16384 float4s, row = 64 float4s
    out4[gid] = in4[n * 16384u + row * 64u + col4];
}

extern "C" void kernel_launch(void* const* d_in, const int* in_sizes, int n_in,
                              void* d_out, int out_size, void* d_ws, size_t ws_size,
                              hipStream_t stream) {
    const float4* in4 = (const float4*)d_in[0];
    float4* out4 = (float4*)d_out;
    // 16,257,024 float4s total
    unsigned total4 = NIMG * PATCHES * CHUNKS;
    unsigned blocks = total4 / 256u;  // 63504, exact
    image2patch_kernel<<<blocks, 256, 0, stream>>>(in4, out4);
}

// Round 2
// 298.239 us; speedup vs baseline: 1.0010x; 1.0010x over previous
//
#include <hip/hip_runtime.h>

// image2patch / im2col gather, LDS-staged:
//   input  : (32, 8, 256, 256) fp32 -> 256 images of 256x256
//   output : (256, 3969, 64) fp32; patch p: row0=4*(p/63), col0=4*(p%63)
//
// Key geometry: for fixed image n and patch-row pr, all 63 patches read only
// the contiguous 8-row band [4*pr, 4*pr+8) = 8 KB. One block per (n, pr):
//   1) stage band into LDS, fully coalesced float4 loads (2 per thread)
//   2) __syncthreads
//   3) write 63 patches (1008 float4, 16 KB) fully coalesced, gathering
//      from LDS: out chunk (pc, k4) = lds_row[k4>>1][float4 pc + (k4&1)]
// LDS rows padded to 65 float4s so the di-fanout (8 lanes hitting the same
// column) spreads across bank quads instead of 8-way colliding.

constexpr unsigned NPDIM   = 63;            // patch positions per dim
constexpr unsigned PATCHES = NPDIM * NPDIM; // 3969
constexpr unsigned CHUNKS  = 16;            // float4 chunks per 8x8 patch
constexpr unsigned ROWPAD  = 65;            // LDS row stride in float4s

__global__ __launch_bounds__(256) void image2patch_kernel(
    const float4* __restrict__ in4, float4* __restrict__ out4) {
    __shared__ float4 lds4[8 * ROWPAD];     // 8.3 KB

    unsigned bid = blockIdx.x;
    unsigned n   = bid / NPDIM;             // image index, 0..255
    unsigned pr  = bid - n * NPDIM;         // patch row, 0..62

    // ---- stage 8-row band: rows 4*pr .. 4*pr+7, contiguous 2048 floats ----
    // image = 16384 float4s, row = 64 float4s; band start = pr*4*64 = pr*256
    unsigned inbase4 = n * 16384u + pr * 256u;
    unsigned t = threadIdx.x;
    {
        unsigned r0 = t >> 6, c0 = t & 63u;             // i = t
        lds4[r0 * ROWPAD + c0] = in4[inbase4 + t];
        unsigned i1 = t + 256u;
        unsigned r1 = i1 >> 6, c1 = i1 & 63u;           // i = t + 256
        lds4[r1 * ROWPAD + c1] = in4[inbase4 + i1];
    }
    __syncthreads();

    // ---- emit 63 patches = 1008 float4, coalesced ----
    unsigned outbase4 = (n * PATCHES + pr * NPDIM) * CHUNKS;
    #pragma unroll
    for (unsigned it = 0; it < 4; ++it) {
        unsigned i = it * 256u + t;
        if (i < NPDIM * CHUNKS) {                       // 1008
            unsigned pc  = i >> 4;                      // patch col, 0..62
            unsigned k4  = i & 15u;                     // chunk in patch
            unsigned di  = k4 >> 1;                     // row in patch, 0..7
            unsigned dj4 = k4 & 1u;                     // half-row, 0..1
            out4[outbase4 + i] = lds4[di * ROWPAD + pc + dj4];
        }
    }
}

extern "C" void kernel_launch(void* const* d_in, const int* in_sizes, int n_in,
                              void* d_out, int out_size, void* d_ws, size_t ws_size,
                              hipStream_t stream) {
    const float4* in4 = (const float4*)d_in[0];
    float4* out4 = (float4*)d_out;
    unsigned blocks = 256u * NPDIM;   // one block per (image, patch-row) = 16128
    image2patch_kernel<<<blocks, 256, 0, stream>>>(in4, out4);
}